// Round 10
// baseline (213.364 us; speedup 1.0000x reference)
//
#include <hip/hip_runtime.h>
#include <math.h>

// MHSA round 10: qkv without LDS staging — fragments loaded straight from
// k-slab global layout into registers (register double-buffer, no barriers).
#define WH 2048
#define DM 256
#define NHD 8
#define DH 32
#define NB 8

typedef __attribute__((ext_vector_type(8))) short short8;
typedef __attribute__((ext_vector_type(4))) short short4v;
typedef __attribute__((ext_vector_type(4))) float f32x4;

__device__ __forceinline__ unsigned short bf16_rn(float f) {
    unsigned u = __float_as_uint(f);
    return (unsigned short)((u + 0x8000u) >> 16);
}
__device__ __forceinline__ float bf16_to_f(unsigned short h) {
    return __uint_as_float(((unsigned)h) << 16);
}
__device__ __forceinline__ unsigned pack_bf16_rtz(float f1, float f0) {
    return __builtin_amdgcn_perm(__float_as_uint(f1), __float_as_uint(f0), 0x07060302);
}
__device__ __forceinline__ void glds16(const void* g, void* l) {
    __builtin_amdgcn_global_load_lds(
        (const __attribute__((address_space(1))) unsigned int*)g,
        (__attribute__((address_space(3))) unsigned int*)l, 16, 0, 0);
}

// ---------------- prep: X split (blocks 0..2047) + W transpose/split (2048..2095) ----------------
__global__ __launch_bounds__(256) void prep(
    const float* __restrict__ X,
    const float* __restrict__ Wq, const float* __restrict__ Wk, const float* __restrict__ Wv,
    unsigned short* __restrict__ Xhi, unsigned short* __restrict__ Xlo,
    unsigned short* __restrict__ WThi, unsigned short* __restrict__ WTlo)
{
    const int bid = blockIdx.x;
    if (bid < 2048) {
        const size_t i = ((size_t)bid * 256 + threadIdx.x) * 8;
        const int row = (int)(i >> 8);
        const int k   = (int)(i & 255);
        const size_t dst = ((size_t)(k >> 5) * 16384 + row) * 32 + (k & 31);
        float4 a = *(const float4*)&X[i];
        float4 b = *(const float4*)&X[i + 4];
        float v[8] = {a.x, a.y, a.z, a.w, b.x, b.y, b.z, b.w};
        short8 hi, lo;
        #pragma unroll
        for (int e = 0; e < 8; e++) {
            unsigned short hb = bf16_rn(v[e]);
            hi[e] = (short)hb;
            lo[e] = (short)bf16_rn(v[e] - bf16_to_f(hb));
        }
        *(short8*)&Xhi[dst] = hi;
        *(short8*)&Xlo[dst] = lo;
    } else {
        const int b2 = bid - 2048;           // 0..47
        const int z = b2 >> 4, xb = b2 & 15;
        const float* W = (z == 0) ? Wq : ((z == 1) ? Wk : Wv);
        const size_t zoff = (size_t)z * DM * DM;
        const int tg = xb * 256 + threadIdx.x;
        #pragma unroll
        for (int j = 0; j < 4; j++) {
            const int f = tg + j * 4096;
            const int k  = f >> 6;
            const int n0 = (f & 63) * 4;
            float4 v = *(const float4*)&W[(size_t)k * DM + n0];
            float vv[4] = {v.x, v.y, v.z, v.w};
            #pragma unroll
            for (int i = 0; i < 4; i++) {
                unsigned short hb = bf16_rn(vv[i]);
                const size_t dst = zoff + ((size_t)(k >> 5) * 256 + n0 + i) * 32 + (k & 31);
                WThi[dst] = hb;
                WTlo[dst] = bf16_rn(vv[i] - bf16_to_f(hb));
            }
        }
    }
}

// ---------------- QKV projection: register-direct split-bf16 MFMA ----------------
// No staging LDS: a lane's A/B fragment is 16B contiguous in the k-slab layout,
// and a wave's 16 fragments tile a contiguous 1KB block (fully coalesced).
// Register double-buffer hides VMEM latency; zero barriers in the K-loop.
__global__ __launch_bounds__(256) void qkv_mfma(
    const unsigned short* __restrict__ Xhi, const unsigned short* __restrict__ Xlo,
    const unsigned short* __restrict__ WThi, const unsigned short* __restrict__ WTlo,
    const float* __restrict__ bq, const float* __restrict__ bk, const float* __restrict__ bv,
    unsigned short* __restrict__ Qhi, unsigned short* __restrict__ Qlo,
    unsigned short* __restrict__ KV)
{
    __shared__ __align__(16) unsigned Tp[64 * 132];   // epilogue transpose only

    const int z = blockIdx.z;
    const float* bias = (z == 0) ? bq : ((z == 1) ? bk : bv);
    const size_t zoff = (size_t)z * DM * DM;

    const int tid  = threadIdx.x;
    const int w    = tid >> 6;
    const int lane = tid & 63;
    const int col  = lane & 15;
    const int quad = lane >> 4;
    const int wr = w >> 1, wc = w & 1;
    const int bm = blockIdx.x * 128;
    const int bn = blockIdx.y * 128;

    // fragment base offsets (elements)
    const size_t aoffs = (size_t)(bm + wr * 64 + col) * 32 + quad * 8;         // + kb*524288 + mi*512
    const size_t boffs = zoff + (size_t)(bn + wc * 64 + col) * 32 + quad * 8;  // + kb*8192   + ni*512

    short8 ah[2][4], al[2][4], bh[2][4], bl[2][4];
    auto load = [&](int kb, int buf) {
        #pragma unroll
        for (int i = 0; i < 4; i++) {
            const size_t ao = aoffs + (size_t)kb * 524288 + i * 512;
            ah[buf][i] = *(const short8*)&Xhi[ao];
            al[buf][i] = *(const short8*)&Xlo[ao];
            const size_t bo = boffs + (size_t)kb * 8192 + i * 512;
            bh[buf][i] = *(const short8*)&WThi[bo];
            bl[buf][i] = *(const short8*)&WTlo[bo];
        }
    };

    f32x4 acc[4][4];
    #pragma unroll
    for (int mi = 0; mi < 4; mi++)
        #pragma unroll
        for (int ni = 0; ni < 4; ni++) acc[mi][ni] = (f32x4){0.f, 0.f, 0.f, 0.f};

    load(0, 0);
    #pragma unroll
    for (int kb = 0; kb < 8; kb++) {
        const int b = kb & 1;
        if (kb < 7) load(kb + 1, b ^ 1);
        #pragma unroll
        for (int mi = 0; mi < 4; mi++)
            #pragma unroll
            for (int ni = 0; ni < 4; ni++) {
                acc[mi][ni] = __builtin_amdgcn_mfma_f32_16x16x32_bf16(al[b][mi], bh[b][ni], acc[mi][ni], 0, 0, 0);
                acc[mi][ni] = __builtin_amdgcn_mfma_f32_16x16x32_bf16(ah[b][mi], bl[b][ni], acc[mi][ni], 0, 0, 0);
                acc[mi][ni] = __builtin_amdgcn_mfma_f32_16x16x32_bf16(ah[b][mi], bh[b][ni], acc[mi][ni], 0, 0, 0);
            }
    }

    // ---- vectorized epilogue through LDS (packed hi|lo uints) ----
    const int n   = bm >> 11;
    const int wqb = bm & (WH - 1);
    const float qsc = (z == 0) ? 8.1611159f : 1.0f;  // sqrt(32)*log2(e) folded into Q

    #pragma unroll
    for (int p = 0; p < 2; p++) {
        if (wr == p) {
            #pragma unroll
            for (int mi = 0; mi < 4; mi++)
                #pragma unroll
                for (int ni = 0; ni < 4; ni++) {
                    const int lc = wc * 64 + ni * 16 + col;
                    const float bb = bias[bn + lc];
                    #pragma unroll
                    for (int r = 0; r < 4; r++) {
                        float v = (acc[mi][ni][r] + bb) * qsc;
                        unsigned short hb = bf16_rn(v);
                        unsigned short lb = bf16_rn(v - bf16_to_f(hb));
                        Tp[(mi * 16 + quad * 4 + r) * 132 + lc] =
                            (unsigned)hb | ((unsigned)lb << 16);
                    }
                }
        }
        __syncthreads();
        if (z == 2) {
            const int c = tid >> 1, half = tid & 1;
            const int coln = bn + c, h = coln >> 5, d = coln & 31;
            const int key0 = wqb + p * 64 + half * 32;
            const int t = key0 >> 6, k6 = key0 & 63;
            unsigned short* dst =
                &KV[(((size_t)(n * NHD + h) * 32 + t) * 6144) + 4096 + d * 64 + k6];
            unsigned hi[16];
            #pragma unroll
            for (int jj = 0; jj < 16; jj++) {
                unsigned u0 = Tp[(half * 32 + 2 * jj    ) * 132 + c];
                unsigned u1 = Tp[(half * 32 + 2 * jj + 1) * 132 + c];
                hi[jj] = __builtin_amdgcn_perm(u1, u0, 0x05040100);
            }
            #pragma unroll
            for (int s = 0; s < 4; s++)
                *(uint4*)&dst[s * 8] = make_uint4(hi[4*s], hi[4*s+1], hi[4*s+2], hi[4*s+3]);
        } else if (z == 1) {
            const int lr = tid >> 2, seg = tid & 3;
            const int h = (bn + seg * 32) >> 5;
            const int key = wqb + p * 64 + lr;
            const int t = key >> 6, k6 = key & 63;
            unsigned short* blobK =
                &KV[(((size_t)(n * NHD + h) * 32 + t) * 6144) + k6 * 32];
            #pragma unroll
            for (int s = 0; s < 4; s++) {
                unsigned u[8], hi[4], lo[4];
                *(uint4*)&u[0] = *(uint4*)&Tp[lr * 132 + seg * 32 + s * 8];
                *(uint4*)&u[4] = *(uint4*)&Tp[lr * 132 + seg * 32 + s * 8 + 4];
                #pragma unroll
                for (int jj = 0; jj < 4; jj++) {
                    hi[jj] = __builtin_amdgcn_perm(u[2*jj+1], u[2*jj], 0x05040100);
                    lo[jj] = __builtin_amdgcn_perm(u[2*jj+1], u[2*jj], 0x07060302);
                }
                *(uint4*)&blobK[s * 8]        = make_uint4(hi[0], hi[1], hi[2], hi[3]);
                *(uint4*)&blobK[2048 + s * 8] = make_uint4(lo[0], lo[1], lo[2], lo[3]);
            }
        } else {
            const int lr = tid >> 2, seg = tid & 3;
            const int h = (bn + seg * 32) >> 5;
            const size_t off = ((size_t)((n * NHD + h) * WH) + wqb + p * 64 + lr) * DH;
            #pragma unroll
            for (int s = 0; s < 4; s++) {
                unsigned u[8], hi[4], lo[4];
                *(uint4*)&u[0] = *(uint4*)&Tp[lr * 132 + seg * 32 + s * 8];
                *(uint4*)&u[4] = *(uint4*)&Tp[lr * 132 + seg * 32 + s * 8 + 4];
                #pragma unroll
                for (int jj = 0; jj < 4; jj++) {
                    hi[jj] = __builtin_amdgcn_perm(u[2*jj+1], u[2*jj], 0x05040100);
                    lo[jj] = __builtin_amdgcn_perm(u[2*jj+1], u[2*jj], 0x07060302);
                }
                *(uint4*)&Qhi[off + s * 8] = make_uint4(hi[0], hi[1], hi[2], hi[3]);
                *(uint4*)&Qlo[off + s * 8] = make_uint4(lo[0], lo[1], lo[2], lo[3]);
            }
        }
        __syncthreads();
    }
}

// ---------------- MFMA flash attention: 64-key blob tiles, VALU diet ----------------
__global__ __launch_bounds__(256, 4) void attn(
    const unsigned short* __restrict__ Qhi, const unsigned short* __restrict__ Qlo,
    const unsigned short* __restrict__ KV,  const float* __restrict__ X,
    float* __restrict__ Out)
{
    __shared__ __align__(16) unsigned short B[2][6144];   // 12KB blob x2

    const int tid  = threadIdx.x;
    const int w    = tid >> 6;
    const int lane = tid & 63;
    const int col  = lane & 15;
    const int quad = lane >> 4;
    const int nh   = blockIdx.y;
    const int q0   = blockIdx.x * 128;
    const size_t qbase = (size_t)nh * WH * DH;
    const char* blob = (const char*)(KV + (size_t)nh * 196608);

    short8 qh[2], ql[2];
    #pragma unroll
    for (int f = 0; f < 2; f++) {
        const int qrow = q0 + f * 64 + w * 16 + col;
        qh[f] = *(const short8*)&Qhi[qbase + (size_t)qrow * DH + quad * 8];
        ql[f] = *(const short8*)&Qlo[qbase + (size_t)qrow * DH + quad * 8];
    }

    f32x4 o00 = {0.f,0.f,0.f,0.f}, o01 = {0.f,0.f,0.f,0.f};
    f32x4 o10 = {0.f,0.f,0.f,0.f}, o11 = {0.f,0.f,0.f,0.f};
    f32x4 la0 = {0.f,0.f,0.f,0.f}, la1 = {0.f,0.f,0.f,0.f};   // l accumulators
    float mr0 = 0.f, mr1 = 0.f;

    const char* gseg[3];
    int loseg[3];
    #pragma unroll
    for (int j = 0; j < 3; j++) {
        const int s = w * 3 + j;
        int loff;
        if (s < 8) loff = (lane >> 2) * 64  + (((lane & 3) ^ ((lane >> 3) & 3)) << 4);
        else       loff = (lane >> 3) * 128 + (((lane & 7) ^ ((lane >> 3) & 7)) << 4);
        gseg[j] = blob + s * 1024 + loff;
        loseg[j] = s * 512;
    }

    auto issue = [&](int t, int b) {
        #pragma unroll
        for (int j = 0; j < 3; j++)
            glds16(gseg[j] + (size_t)t * 12288, &B[b][loseg[j]]);
    };

    const int sw = (col >> 1) & 3;
    const short4v ones = {(short)0x3F80, (short)0x3F80, (short)0x3F80, (short)0x3F80};

    auto body = [&](int b) {
        const unsigned short* Bp = &B[b][0];
        short8 kh[4], kl[4];
        #pragma unroll
        for (int kc = 0; kc < 4; kc++) {
            const int ro = (col + kc * 16) * 32 + (quad ^ sw) * 8;
            kh[kc] = *(const short8*)&Bp[ro];
            kl[kc] = *(const short8*)&Bp[2048 + ro];
        }
        short4v va[4][2];
        #pragma unroll
        for (int kc = 0; kc < 4; kc++) {
            const int cl = kc * 2 + (quad >> 1);
            const int co = ((cl ^ (col & 7)) << 3) + (quad & 1) * 4;
            va[kc][0] = *(const short4v*)&Bp[4096 + (col     ) * 64 + co];
            va[kc][1] = *(const short4v*)&Bp[4096 + (col + 16) * 64 + co];
        }
        #pragma unroll
        for (int f = 0; f < 2; f++) {
            f32x4 s[4];
            #pragma unroll
            for (int kc = 0; kc < 4; kc++) {
                f32x4 a = {0.f, 0.f, 0.f, 0.f};
                a = __builtin_amdgcn_mfma_f32_16x16x32_bf16(kh[kc], ql[f], a, 0, 0, 0);
                a = __builtin_amdgcn_mfma_f32_16x16x32_bf16(kl[kc], qh[f], a, 0, 0, 0);
                a = __builtin_amdgcn_mfma_f32_16x16x32_bf16(kh[kc], qh[f], a, 0, 0, 0);
                s[kc] = a;
            }
            float mx = s[0][0];
            #pragma unroll
            for (int kc = 0; kc < 4; kc++)
                #pragma unroll
                for (int r = 0; r < 4; r++) mx = fmaxf(mx, s[kc][r]);
            mx = fmaxf(mx, __shfl_xor(mx, 16));
            mx = fmaxf(mx, __shfl_xor(mx, 32));

            float& mrf = f ? mr1 : mr0;
            f32x4& a0 = f ? o10 : o00;
            f32x4& a1 = f ? o11 : o01;
            f32x4& la = f ? la1 : la0;
            const float mnew = fmaxf(mrf, mx);
            if (__any(mx > mrf)) {
                const float alpha = __builtin_amdgcn_exp2f(mrf - mnew);
                #pragma unroll
                for (int r = 0; r < 4; r++) { a0[r] *= alpha; a1[r] *= alpha; }
                la[0] *= alpha;
            }
            mrf = mnew;

            short4v pb[4];
            #pragma unroll
            for (int kc = 0; kc < 4; kc++) {
                const float p0 = __builtin_amdgcn_exp2f(s[kc][0] - mnew);
                const float p1 = __builtin_amdgcn_exp2f(s[kc][1] - mnew);
                const float p2 = __builtin_amdgcn_exp2f(s[kc][2] - mnew);
                const float p3 = __builtin_amdgcn_exp2f(s[kc][3] - mnew);
                union { short4v v; unsigned u[2]; } P;
                P.u[0] = pack_bf16_rtz(p1, p0);
                P.u[1] = pack_bf16_rtz(p3, p2);
                pb[kc] = P.v;
            }
            #pragma unroll
            for (int kc = 0; kc < 4; kc++) {
                a0 = __builtin_amdgcn_mfma_f32_16x16x16bf16_1k(va[kc][0], pb[kc], a0, 0, 0, 0);
                a1 = __builtin_amdgcn_mfma_f32_16x16x16bf16_1k(va[kc][1], pb[kc], a1, 0, 0, 0);
                la = __builtin_amdgcn_mfma_f32_16x16x16bf16_1k(ones,      pb[kc], la, 0, 0, 0);
            }
        }
    };

    issue(0, 0);
    __syncthreads();
    for (int t2 = 0; t2 < 16; t2++) {
        issue(2 * t2 + 1, 1);
        body(0);
        __syncthreads();
        if (t2 < 15) issue(2 * t2 + 2, 0);
        body(1);
        __syncthreads();
    }

    const int n = nh >> 3, h = nh & 7;
    #pragma unroll
    for (int f = 0; f < 2; f++) {
        const float inv = 1.f / (f ? la1[0] : la0[0]);
        const f32x4& a0 = f ? o10 : o00;
        const f32x4& a1 = f ? o11 : o01;
        const int qrow = q0 + f * 64 + w * 16 + col;
        const size_t a = ((size_t)n * WH + qrow) * DM + h * DH + quad * 4;
        float4 x0 = *(const float4*)&X[a];
        float4 y0;
        y0.x = a0[0] * inv + x0.x;
        y0.y = a0[1] * inv + x0.y;
        y0.z = a0[2] * inv + x0.z;
        y0.w = a0[3] * inv + x0.w;
        *(float4*)&Out[a] = y0;
        float4 x1 = *(const float4*)&X[a + 16];
        float4 y1;
        y1.x = a1[0] * inv + x1.x;
        y1.y = a1[1] * inv + x1.y;
        y1.z = a1[2] * inv + x1.z;
        y1.w = a1[3] * inv + x1.w;
        *(float4*)&Out[a + 16] = y1;
    }
}

extern "C" void kernel_launch(void* const* d_in, const int* in_sizes, int n_in,
                              void* d_out, int out_size, void* d_ws, size_t ws_size,
                              hipStream_t stream) {
    const float* x  = (const float*)d_in[0];
    const float* Wq = (const float*)d_in[1];
    const float* bq = (const float*)d_in[2];
    const float* Wk = (const float*)d_in[3];
    const float* bk = (const float*)d_in[4];
    const float* Wv = (const float*)d_in[5];
    const float* bv = (const float*)d_in[6];
    float* out = (float*)d_out;

    const size_t elems = (size_t)NB * WH * DM;   // 4,194,304
    unsigned short* Qhi  = (unsigned short*)d_ws;
    unsigned short* Qlo  = Qhi + elems;
    unsigned short* KV   = Qlo + elems;                    // 64 heads x 32 tiles x 6144
    unsigned short* WThi = KV  + (size_t)64 * 32 * 6144;
    unsigned short* WTlo = WThi + (size_t)3 * DM * DM;

    // X hi/lo slabs live in d_out (16.78 MB); attn fully overwrites d_out after.
    unsigned short* Xhi = (unsigned short*)d_out;
    unsigned short* Xlo = Xhi + elems;

    prep<<<2096, 256, 0, stream>>>(x, Wq, Wk, Wv, Xhi, Xlo, WThi, WTlo);

    dim3 gg(128, 2, 3);
    qkv_mfma<<<gg, 256, 0, stream>>>(Xhi, Xlo, WThi, WTlo, bq, bk, bv,
                                     Qhi, Qlo, KV);

    dim3 ga(WH / 128, NB * NHD);   // (16, 64) = 1024 blocks
    attn<<<ga, 256, 0, stream>>>(Qhi, Qlo, KV, x, out);
}

// Round 11
// 206.684 us; speedup vs baseline: 1.0323x; 1.0323x over previous
//
#include <hip/hip_runtime.h>
#include <math.h>

// MHSA round 11: revert qkv to round-9 (LDS DMA single-buffer, 3 blocks/CU);
// attn switched to 64-q blocks (grid 2048) for 6 blocks/CU occupancy.
#define WH 2048
#define DM 256
#define NHD 8
#define DH 32
#define NB 8

typedef __attribute__((ext_vector_type(8))) short short8;
typedef __attribute__((ext_vector_type(4))) short short4v;
typedef __attribute__((ext_vector_type(4))) float f32x4;

__device__ __forceinline__ unsigned short bf16_rn(float f) {
    unsigned u = __float_as_uint(f);
    return (unsigned short)((u + 0x8000u) >> 16);
}
__device__ __forceinline__ float bf16_to_f(unsigned short h) {
    return __uint_as_float(((unsigned)h) << 16);
}
__device__ __forceinline__ unsigned pack_bf16_rtz(float f1, float f0) {
    return __builtin_amdgcn_perm(__float_as_uint(f1), __float_as_uint(f0), 0x07060302);
}
__device__ __forceinline__ void glds16(const void* g, void* l) {
    __builtin_amdgcn_global_load_lds(
        (const __attribute__((address_space(1))) unsigned int*)g,
        (__attribute__((address_space(3))) unsigned int*)l, 16, 0, 0);
}

// ---------------- prep: X split (blocks 0..2047) + W transpose/split (2048..2095) ----------------
__global__ __launch_bounds__(256) void prep(
    const float* __restrict__ X,
    const float* __restrict__ Wq, const float* __restrict__ Wk, const float* __restrict__ Wv,
    unsigned short* __restrict__ Xhi, unsigned short* __restrict__ Xlo,
    unsigned short* __restrict__ WThi, unsigned short* __restrict__ WTlo)
{
    const int bid = blockIdx.x;
    if (bid < 2048) {
        const size_t i = ((size_t)bid * 256 + threadIdx.x) * 8;
        const int row = (int)(i >> 8);
        const int k   = (int)(i & 255);
        const size_t dst = ((size_t)(k >> 5) * 16384 + row) * 32 + (k & 31);
        float4 a = *(const float4*)&X[i];
        float4 b = *(const float4*)&X[i + 4];
        float v[8] = {a.x, a.y, a.z, a.w, b.x, b.y, b.z, b.w};
        short8 hi, lo;
        #pragma unroll
        for (int e = 0; e < 8; e++) {
            unsigned short hb = bf16_rn(v[e]);
            hi[e] = (short)hb;
            lo[e] = (short)bf16_rn(v[e] - bf16_to_f(hb));
        }
        *(short8*)&Xhi[dst] = hi;
        *(short8*)&Xlo[dst] = lo;
    } else {
        const int b2 = bid - 2048;           // 0..47
        const int z = b2 >> 4, xb = b2 & 15;
        const float* W = (z == 0) ? Wq : ((z == 1) ? Wk : Wv);
        const size_t zoff = (size_t)z * DM * DM;
        const int tg = xb * 256 + threadIdx.x;
        #pragma unroll
        for (int j = 0; j < 4; j++) {
            const int f = tg + j * 4096;
            const int k  = f >> 6;
            const int n0 = (f & 63) * 4;
            float4 v = *(const float4*)&W[(size_t)k * DM + n0];
            float vv[4] = {v.x, v.y, v.z, v.w};
            #pragma unroll
            for (int i = 0; i < 4; i++) {
                unsigned short hb = bf16_rn(vv[i]);
                const size_t dst = zoff + ((size_t)(k >> 5) * 256 + n0 + i) * 32 + (k & 31);
                WThi[dst] = hb;
                WTlo[dst] = bf16_rn(vv[i] - bf16_to_f(hb));
            }
        }
    }
}

// ---------------- QKV projection: split-bf16 MFMA, single-buffer DMA (round-9) ----------------
__global__ __launch_bounds__(256, 3) void qkv_mfma(
    const unsigned short* __restrict__ Xhi, const unsigned short* __restrict__ Xlo,
    const unsigned short* __restrict__ WThi, const unsigned short* __restrict__ WTlo,
    const float* __restrict__ bq, const float* __restrict__ bk, const float* __restrict__ bv,
    unsigned short* __restrict__ Qhi, unsigned short* __restrict__ Qlo,
    unsigned short* __restrict__ KV)
{
    __shared__ __align__(16) unsigned short arena[16896];

    const int z = blockIdx.z;
    const float* bias = (z == 0) ? bq : ((z == 1) ? bk : bv);
    const size_t zoff = (size_t)z * DM * DM;

    const int tid  = threadIdx.x;
    const int w    = tid >> 6;
    const int lane = tid & 63;
    const int col  = lane & 15;
    const int quad = lane >> 4;
    const int wr = w >> 1, wc = w & 1;
    const int bm = blockIdx.x * 128;
    const int bn = blockIdx.y * 128;

    const int perm16 = (((lane & 3) ^ ((lane >> 3) & 3))) * 16;
    const char* glane; size_t kstr;
    if (w == 0)      { glane = (const char*)Xhi + (size_t)(bm + (lane >> 2)) * 64 + perm16; kstr = (size_t)16384 * 64; }
    else if (w == 1) { glane = (const char*)Xlo + (size_t)(bm + (lane >> 2)) * 64 + perm16; kstr = (size_t)16384 * 64; }
    else if (w == 2) { glane = (const char*)(WThi + zoff) + (size_t)(bn + (lane >> 2)) * 64 + perm16; kstr = 256 * 64; }
    else             { glane = (const char*)(WTlo + zoff) + (size_t)(bn + (lane >> 2)) * 64 + perm16; kstr = 256 * 64; }

    auto issue = [&](int kb) {
        const char* g0 = glane + (size_t)kb * kstr;
        unsigned short* l0 = &arena[w * 4096];
        #pragma unroll
        for (int g = 0; g < 8; g++)
            glds16(g0 + (size_t)g * 1024, l0 + g * 512);
    };

    f32x4 acc[4][4];
    #pragma unroll
    for (int mi = 0; mi < 4; mi++)
        #pragma unroll
        for (int ni = 0; ni < 4; ni++) acc[mi][ni] = (f32x4){0.f, 0.f, 0.f, 0.f};

    const int sw = (col >> 1) & 3;
    const int fO = (quad ^ sw) * 8;

    for (int kb = 0; kb < 8; kb++) {
        issue(kb);
        __syncthreads();

        short8 ah[4], al[4], bh[4], bl[4];
        #pragma unroll
        for (int mi = 0; mi < 4; mi++) {
            const int ro = (wr * 64 + mi * 16 + col) * 32 + fO;
            ah[mi] = *(const short8*)&arena[ro];
            al[mi] = *(const short8*)&arena[4096 + ro];
        }
        #pragma unroll
        for (int ni = 0; ni < 4; ni++) {
            const int no = (wc * 64 + ni * 16 + col) * 32 + fO;
            bh[ni] = *(const short8*)&arena[8192 + no];
            bl[ni] = *(const short8*)&arena[12288 + no];
        }
        #pragma unroll
        for (int mi = 0; mi < 4; mi++)
            #pragma unroll
            for (int ni = 0; ni < 4; ni++) {
                acc[mi][ni] = __builtin_amdgcn_mfma_f32_16x16x32_bf16(al[mi], bh[ni], acc[mi][ni], 0, 0, 0);
                acc[mi][ni] = __builtin_amdgcn_mfma_f32_16x16x32_bf16(ah[mi], bl[ni], acc[mi][ni], 0, 0, 0);
                acc[mi][ni] = __builtin_amdgcn_mfma_f32_16x16x32_bf16(ah[mi], bh[ni], acc[mi][ni], 0, 0, 0);
            }
        __syncthreads();
    }

    // ---- vectorized epilogue through LDS (packed hi|lo uints) ----
    unsigned* Tp = (unsigned*)arena;                 // [64][132]
    const int n   = bm >> 11;
    const int wqb = bm & (WH - 1);
    const float qsc = (z == 0) ? 8.1611159f : 1.0f;  // sqrt(32)*log2(e) folded into Q

    #pragma unroll
    for (int p = 0; p < 2; p++) {
        if (wr == p) {
            #pragma unroll
            for (int mi = 0; mi < 4; mi++)
                #pragma unroll
                for (int ni = 0; ni < 4; ni++) {
                    const int lc = wc * 64 + ni * 16 + col;
                    const float bb = bias[bn + lc];
                    #pragma unroll
                    for (int r = 0; r < 4; r++) {
                        float v = (acc[mi][ni][r] + bb) * qsc;
                        unsigned short hb = bf16_rn(v);
                        unsigned short lb = bf16_rn(v - bf16_to_f(hb));
                        Tp[(mi * 16 + quad * 4 + r) * 132 + lc] =
                            (unsigned)hb | ((unsigned)lb << 16);
                    }
                }
        }
        __syncthreads();
        if (z == 2) {
            const int c = tid >> 1, half = tid & 1;
            const int coln = bn + c, h = coln >> 5, d = coln & 31;
            const int key0 = wqb + p * 64 + half * 32;
            const int t = key0 >> 6, k6 = key0 & 63;
            unsigned short* dst =
                &KV[(((size_t)(n * NHD + h) * 32 + t) * 6144) + 4096 + d * 64 + k6];
            unsigned hi[16];
            #pragma unroll
            for (int jj = 0; jj < 16; jj++) {
                unsigned u0 = Tp[(half * 32 + 2 * jj    ) * 132 + c];
                unsigned u1 = Tp[(half * 32 + 2 * jj + 1) * 132 + c];
                hi[jj] = __builtin_amdgcn_perm(u1, u0, 0x05040100);
            }
            #pragma unroll
            for (int s = 0; s < 4; s++)
                *(uint4*)&dst[s * 8] = make_uint4(hi[4*s], hi[4*s+1], hi[4*s+2], hi[4*s+3]);
        } else if (z == 1) {
            const int lr = tid >> 2, seg = tid & 3;
            const int h = (bn + seg * 32) >> 5;
            const int key = wqb + p * 64 + lr;
            const int t = key >> 6, k6 = key & 63;
            unsigned short* blobK =
                &KV[(((size_t)(n * NHD + h) * 32 + t) * 6144) + k6 * 32];
            #pragma unroll
            for (int s = 0; s < 4; s++) {
                unsigned u[8], hi[4], lo[4];
                *(uint4*)&u[0] = *(uint4*)&Tp[lr * 132 + seg * 32 + s * 8];
                *(uint4*)&u[4] = *(uint4*)&Tp[lr * 132 + seg * 32 + s * 8 + 4];
                #pragma unroll
                for (int jj = 0; jj < 4; jj++) {
                    hi[jj] = __builtin_amdgcn_perm(u[2*jj+1], u[2*jj], 0x05040100);
                    lo[jj] = __builtin_amdgcn_perm(u[2*jj+1], u[2*jj], 0x07060302);
                }
                *(uint4*)&blobK[s * 8]        = make_uint4(hi[0], hi[1], hi[2], hi[3]);
                *(uint4*)&blobK[2048 + s * 8] = make_uint4(lo[0], lo[1], lo[2], lo[3]);
            }
        } else {
            const int lr = tid >> 2, seg = tid & 3;
            const int h = (bn + seg * 32) >> 5;
            const size_t off = ((size_t)((n * NHD + h) * WH) + wqb + p * 64 + lr) * DH;
            #pragma unroll
            for (int s = 0; s < 4; s++) {
                unsigned u[8], hi[4], lo[4];
                *(uint4*)&u[0] = *(uint4*)&Tp[lr * 132 + seg * 32 + s * 8];
                *(uint4*)&u[4] = *(uint4*)&Tp[lr * 132 + seg * 32 + s * 8 + 4];
                #pragma unroll
                for (int jj = 0; jj < 4; jj++) {
                    hi[jj] = __builtin_amdgcn_perm(u[2*jj+1], u[2*jj], 0x05040100);
                    lo[jj] = __builtin_amdgcn_perm(u[2*jj+1], u[2*jj], 0x07060302);
                }
                *(uint4*)&Qhi[off + s * 8] = make_uint4(hi[0], hi[1], hi[2], hi[3]);
                *(uint4*)&Qlo[off + s * 8] = make_uint4(lo[0], lo[1], lo[2], lo[3]);
            }
        }
        __syncthreads();
    }
}

// ---------------- MFMA flash attention: 64-q blocks for occupancy ----------------
__global__ __launch_bounds__(256, 6) void attn(
    const unsigned short* __restrict__ Qhi, const unsigned short* __restrict__ Qlo,
    const unsigned short* __restrict__ KV,  const float* __restrict__ X,
    float* __restrict__ Out)
{
    __shared__ __align__(16) unsigned short B[2][6144];   // 12KB blob x2

    const int tid  = threadIdx.x;
    const int w    = tid >> 6;
    const int lane = tid & 63;
    const int col  = lane & 15;
    const int quad = lane >> 4;
    const int nh   = blockIdx.y;
    const int q0   = blockIdx.x * 64;
    const size_t qbase = (size_t)nh * WH * DH;
    const char* blob = (const char*)(KV + (size_t)nh * 196608);

    const int qrow = q0 + w * 16 + col;
    const short8 qh = *(const short8*)&Qhi[qbase + (size_t)qrow * DH + quad * 8];
    const short8 ql = *(const short8*)&Qlo[qbase + (size_t)qrow * DH + quad * 8];

    f32x4 o0 = {0.f,0.f,0.f,0.f}, o1 = {0.f,0.f,0.f,0.f};
    f32x4 la = {0.f,0.f,0.f,0.f};   // l accumulator (elem 0 meaningful)
    float mr = 0.f;

    const char* gseg[3];
    int loseg[3];
    #pragma unroll
    for (int j = 0; j < 3; j++) {
        const int s = w * 3 + j;
        int loff;
        if (s < 8) loff = (lane >> 2) * 64  + (((lane & 3) ^ ((lane >> 3) & 3)) << 4);
        else       loff = (lane >> 3) * 128 + (((lane & 7) ^ ((lane >> 3) & 7)) << 4);
        gseg[j] = blob + s * 1024 + loff;
        loseg[j] = s * 512;
    }

    auto issue = [&](int t, int b) {
        #pragma unroll
        for (int j = 0; j < 3; j++)
            glds16(gseg[j] + (size_t)t * 12288, &B[b][loseg[j]]);
    };

    const int sw = (col >> 1) & 3;
    const short4v ones = {(short)0x3F80, (short)0x3F80, (short)0x3F80, (short)0x3F80};

    auto body = [&](int b) {
        const unsigned short* Bp = &B[b][0];
        short8 kh[4], kl[4];
        #pragma unroll
        for (int kc = 0; kc < 4; kc++) {
            const int ro = (col + kc * 16) * 32 + (quad ^ sw) * 8;
            kh[kc] = *(const short8*)&Bp[ro];
            kl[kc] = *(const short8*)&Bp[2048 + ro];
        }
        short4v va[4][2];
        #pragma unroll
        for (int kc = 0; kc < 4; kc++) {
            const int cl = kc * 2 + (quad >> 1);
            const int co = ((cl ^ (col & 7)) << 3) + (quad & 1) * 4;
            va[kc][0] = *(const short4v*)&Bp[4096 + (col     ) * 64 + co];
            va[kc][1] = *(const short4v*)&Bp[4096 + (col + 16) * 64 + co];
        }
        f32x4 s[4];
        #pragma unroll
        for (int kc = 0; kc < 4; kc++) {
            f32x4 a = {0.f, 0.f, 0.f, 0.f};
            a = __builtin_amdgcn_mfma_f32_16x16x32_bf16(kh[kc], ql, a, 0, 0, 0);
            a = __builtin_amdgcn_mfma_f32_16x16x32_bf16(kl[kc], qh, a, 0, 0, 0);
            a = __builtin_amdgcn_mfma_f32_16x16x32_bf16(kh[kc], qh, a, 0, 0, 0);
            s[kc] = a;
        }
        float mx = s[0][0];
        #pragma unroll
        for (int kc = 0; kc < 4; kc++)
            #pragma unroll
            for (int r = 0; r < 4; r++) mx = fmaxf(mx, s[kc][r]);
        mx = fmaxf(mx, __shfl_xor(mx, 16));
        mx = fmaxf(mx, __shfl_xor(mx, 32));

        const float mnew = fmaxf(mr, mx);
        if (__any(mx > mr)) {   // lazy rescale
            const float alpha = __builtin_amdgcn_exp2f(mr - mnew);
            #pragma unroll
            for (int r = 0; r < 4; r++) { o0[r] *= alpha; o1[r] *= alpha; }
            la[0] *= alpha;
        }
        mr = mnew;

        short4v pb[4];
        #pragma unroll
        for (int kc = 0; kc < 4; kc++) {
            const float p0 = __builtin_amdgcn_exp2f(s[kc][0] - mnew);
            const float p1 = __builtin_amdgcn_exp2f(s[kc][1] - mnew);
            const float p2 = __builtin_amdgcn_exp2f(s[kc][2] - mnew);
            const float p3 = __builtin_amdgcn_exp2f(s[kc][3] - mnew);
            union { short4v v; unsigned u[2]; } P;
            P.u[0] = pack_bf16_rtz(p1, p0);
            P.u[1] = pack_bf16_rtz(p3, p2);
            pb[kc] = P.v;
        }
        #pragma unroll
        for (int kc = 0; kc < 4; kc++) {
            o0 = __builtin_amdgcn_mfma_f32_16x16x16bf16_1k(va[kc][0], pb[kc], o0, 0, 0, 0);
            o1 = __builtin_amdgcn_mfma_f32_16x16x16bf16_1k(va[kc][1], pb[kc], o1, 0, 0, 0);
            la = __builtin_amdgcn_mfma_f32_16x16x16bf16_1k(ones,      pb[kc], la, 0, 0, 0);
        }
    };

    issue(0, 0);
    __syncthreads();
    for (int t2 = 0; t2 < 16; t2++) {
        issue(2 * t2 + 1, 1);
        body(0);
        __syncthreads();
        if (t2 < 15) issue(2 * t2 + 2, 0);
        body(1);
        __syncthreads();
    }

    // epilogue
    const int n = nh >> 3, h = nh & 7;
    const float inv = 1.f / la[0];
    const size_t a = ((size_t)n * WH + qrow) * DM + h * DH + quad * 4;
    float4 x0 = *(const float4*)&X[a];
    float4 y0;
    y0.x = o0[0] * inv + x0.x;
    y0.y = o0[1] * inv + x0.y;
    y0.z = o0[2] * inv + x0.z;
    y0.w = o0[3] * inv + x0.w;
    *(float4*)&Out[a] = y0;
    float4 x1 = *(const float4*)&X[a + 16];
    float4 y1;
    y1.x = o1[0] * inv + x1.x;
    y1.y = o1[1] * inv + x1.y;
    y1.z = o1[2] * inv + x1.z;
    y1.w = o1[3] * inv + x1.w;
    *(float4*)&Out[a + 16] = y1;
}

extern "C" void kernel_launch(void* const* d_in, const int* in_sizes, int n_in,
                              void* d_out, int out_size, void* d_ws, size_t ws_size,
                              hipStream_t stream) {
    const float* x  = (const float*)d_in[0];
    const float* Wq = (const float*)d_in[1];
    const float* bq = (const float*)d_in[2];
    const float* Wk = (const float*)d_in[3];
    const float* bk = (const float*)d_in[4];
    const float* Wv = (const float*)d_in[5];
    const float* bv = (const float*)d_in[6];
    float* out = (float*)d_out;

    const size_t elems = (size_t)NB * WH * DM;   // 4,194,304
    unsigned short* Qhi  = (unsigned short*)d_ws;
    unsigned short* Qlo  = Qhi + elems;
    unsigned short* KV   = Qlo + elems;                    // 64 heads x 32 tiles x 6144
    unsigned short* WThi = KV  + (size_t)64 * 32 * 6144;
    unsigned short* WTlo = WThi + (size_t)3 * DM * DM;

    // X hi/lo slabs live in d_out (16.78 MB); attn fully overwrites d_out after.
    unsigned short* Xhi = (unsigned short*)d_out;
    unsigned short* Xlo = Xhi + elems;

    prep<<<2096, 256, 0, stream>>>(x, Wq, Wk, Wv, Xhi, Xlo, WThi, WTlo);

    dim3 gg(128, 2, 3);
    qkv_mfma<<<gg, 256, 0, stream>>>(Xhi, Xlo, WThi, WTlo, bq, bk, bv,
                                     Qhi, Qlo, KV);

    dim3 ga(WH / 64, NB * NHD);   // (32, 64) = 2048 blocks
    attn<<<ga, 256, 0, stream>>>(Qhi, Qlo, KV, x, out);
}